// Round 14
// baseline (594.540 us; speedup 1.0000x reference)
//
#include <hip/hip_runtime.h>

#define N_ 8
#define C_ 48
#define H_ 48
#define W_ 64
#define HO 384
#define WO 512
#define HW (H_*W_)   // 3072

typedef float f32x4 __attribute__((ext_vector_type(4)));

// out[n][c][h*8+p][w*8+q] = sum_k softmax_k(mask[n][k*64+p*8+q][h][w]) * inp_pad[n][c][h+di-1][w+dj-1]
// R11 zero-LDS + nt-store design, c split 4-ways into 128-thread blocks:
// grid 6144 = 24 blocks/CU total with ~12 resident -> continuous block
// turnover staggers the phases (mask-read / softmax / write) across the chip
// so HBM reads hide under the write stream. Mask loads CACHED (4 cq-siblings
// share rows via L2/L3); stores stay nontemporal.
__global__ __launch_bounds__(128, 6) void raft_up_kernel(
    const float* __restrict__ inp, const float* __restrict__ mask,
    float* __restrict__ out)
{
    const int t   = threadIdx.x;           // 0..127
    const int bid = blockIdx.x;            // ((n*H + h)*4 + pg)*4 + cq
    const int cq  = bid & 3;
    const int pg  = (bid >> 2) & 3;
    const int h   = (bid >> 4) % H_;
    const int n   = bid / (16 * H_);

    const int q4  = t & 1;                 // q quad (q = q4*4 + j)
    const int wi  = t >> 1;                // 0..63 (w coordinate)
    const int c0  = cq * 12;

    // ---- softmax over 9 taps for my 8 planes (pl x 4 q's); f32x4 lanes = j (q)
    f32x4 w[2][9];
    {
        const float* mb = mask + ((size_t)n * 576 + pg * 16 + q4 * 4) * HW
                               + h * W_ + wi;
        #pragma unroll
        for (int pl = 0; pl < 2; ++pl)
            #pragma unroll
            for (int k = 0; k < 9; ++k)
                #pragma unroll
                for (int j = 0; j < 4; ++j)
                    w[pl][k][j] = mb[(size_t)(k * 64 + pl * 8 + j) * HW];

        #pragma unroll
        for (int pl = 0; pl < 2; ++pl) {
            f32x4 mx = w[pl][0];
            #pragma unroll
            for (int k = 1; k < 9; ++k) {
                mx.x = fmaxf(mx.x, w[pl][k].x); mx.y = fmaxf(mx.y, w[pl][k].y);
                mx.z = fmaxf(mx.z, w[pl][k].z); mx.w = fmaxf(mx.w, w[pl][k].w);
            }
            f32x4 s = (f32x4){0.f, 0.f, 0.f, 0.f};
            #pragma unroll
            for (int k = 0; k < 9; ++k) {
                f32x4 e;
                e.x = __expf(w[pl][k].x - mx.x);
                e.y = __expf(w[pl][k].y - mx.y);
                e.z = __expf(w[pl][k].z - mx.z);
                e.w = __expf(w[pl][k].w - mx.w);
                w[pl][k] = e;
                s += e;
            }
            f32x4 inv;
            inv.x = 1.f / s.x; inv.y = 1.f / s.y;
            inv.z = 1.f / s.z; inv.w = 1.f / s.w;
            #pragma unroll
            for (int k = 0; k < 9; ++k) w[pl][k] *= inv;
        }
    }

    // ---- tap validity (zero padding)
    const bool rok0 = (h >= 1), rok2 = (h <= H_ - 2);
    const bool cok0 = (wi >= 1), cok2 = (wi <= W_ - 2);
    const bool ok[3][3] = {
        { rok0 && cok0, rok0, rok0 && cok2 },
        { cok0,         true, cok2         },
        { rok2 && cok0, rok2, rok2 && cok2 },
    };

    const float* ib = inp + (size_t)(n * C_ + c0) * HW + (wi - 1);
    float* outb = out + ((size_t)(n * C_ + c0) * HO + h * 8 + pg * 2) * WO
                      + wi * 8 + q4 * 4;

    for (int cblk = 0; cblk < 3; ++cblk) {
        // taps for 4 channels, read from L2-resident inp (cached loads)
        float tp[4][9];
        #pragma unroll
        for (int di = 0; di < 3; ++di)
            #pragma unroll
            for (int dj = 0; dj < 3; ++dj) {
                const bool o = ok[di][dj];
                #pragma unroll
                for (int cc = 0; cc < 4; ++cc) {
                    const float* p = ib + (size_t)((cblk * 4 + cc) * H_ + h - 1 + di) * W_ + dj;
                    tp[cc][di * 3 + dj] = o ? *p : 0.f;
                }
            }
        #pragma unroll
        for (int cc = 0; cc < 4; ++cc)
            #pragma unroll
            for (int pl = 0; pl < 2; ++pl) {
                f32x4 acc = w[pl][0] * tp[cc][0];
                #pragma unroll
                for (int k = 1; k < 9; ++k)
                    acc += w[pl][k] * tp[cc][k];
                __builtin_nontemporal_store(acc,
                    (f32x4*)(outb + ((size_t)(cblk * 4 + cc) * HO + pl) * WO));
            }
    }
}

extern "C" void kernel_launch(void* const* d_in, const int* in_sizes, int n_in,
                              void* d_out, int out_size, void* d_ws, size_t ws_size,
                              hipStream_t stream) {
    const float* inp  = (const float*)d_in[0];
    const float* mask = (const float*)d_in[1];
    float* out = (float*)d_out;
    const int blocks = N_ * H_ * 4 * 4;   // 8*48*4*4 = 6144
    raft_up_kernel<<<blocks, 128, 0, stream>>>(inp, mask, out);
}

// Round 15
// 86.443 us; speedup vs baseline: 6.8778x; 6.8778x over previous
//
#include <hip/hip_runtime.h>

#define N_ 8
#define C_ 48
#define H_ 48
#define W_ 64
#define HO 384
#define WO 512
#define HW (H_*W_)   // 3072

typedef float f32x4 __attribute__((ext_vector_type(4)));

// out[n][c][h*8+p][w*8+q] = sum_k softmax_k(mask[n][k*64+p*8+q][h][w]) * inp_pad[n][c][h+di-1][w+dj-1]
// R11 (zero-LDS + nt mask loads + nt stores, 84.2us) with ONE change:
// the channel loop is software-pipelined so tap loads for channel i+1 issue
// BEFORE the stores of channel i. gfx9-lineage vmcnt is a single IN-ORDER
// counter for loads+stores; in R11 the wait for taps(i+1) had to drain
// stores(i) first (issued earlier), stalling every wave on the write queue
// each iteration. Reordering gives one iteration of drain slack.
__global__ __launch_bounds__(256, 3) void raft_up_kernel(
    const float* __restrict__ inp, const float* __restrict__ mask,
    float* __restrict__ out)
{
    const int t   = threadIdx.x;
    const int bid = blockIdx.x;            // (n*H + h)*4 + pg
    const int pg  = bid & 3;
    const int h   = (bid >> 2) % H_;
    const int n   = bid / (4 * H_);

    const int tq    = t & 127;
    const int chalf = t >> 7;              // 0: c 0..23, 1: c 24..47
    const int q4    = tq & 1;              // q quad (q = q4*4 + j)
    const int wi    = tq >> 1;             // 0..63 (w coordinate)

    // ---- softmax over 9 taps for my 8 planes (pl x 4 q's); f32x4 lanes = j (q)
    f32x4 w[2][9];
    {
        const float* mb = mask + ((size_t)n * 576 + pg * 16 + q4 * 4) * HW
                               + h * W_ + wi;
        #pragma unroll
        for (int pl = 0; pl < 2; ++pl)
            #pragma unroll
            for (int k = 0; k < 9; ++k)
                #pragma unroll
                for (int j = 0; j < 4; ++j)
                    w[pl][k][j] = __builtin_nontemporal_load(
                        mb + (size_t)(k * 64 + pl * 8 + j) * HW);

        #pragma unroll
        for (int pl = 0; pl < 2; ++pl) {
            f32x4 mx = w[pl][0];
            #pragma unroll
            for (int k = 1; k < 9; ++k) {
                mx.x = fmaxf(mx.x, w[pl][k].x); mx.y = fmaxf(mx.y, w[pl][k].y);
                mx.z = fmaxf(mx.z, w[pl][k].z); mx.w = fmaxf(mx.w, w[pl][k].w);
            }
            f32x4 s = (f32x4){0.f, 0.f, 0.f, 0.f};
            #pragma unroll
            for (int k = 0; k < 9; ++k) {
                f32x4 e;
                e.x = __expf(w[pl][k].x - mx.x);
                e.y = __expf(w[pl][k].y - mx.y);
                e.z = __expf(w[pl][k].z - mx.z);
                e.w = __expf(w[pl][k].w - mx.w);
                w[pl][k] = e;
                s += e;
            }
            f32x4 inv;
            inv.x = 1.f / s.x; inv.y = 1.f / s.y;
            inv.z = 1.f / s.z; inv.w = 1.f / s.w;
            #pragma unroll
            for (int k = 0; k < 9; ++k) w[pl][k] *= inv;
        }
    }

    // ---- tap validity (zero padding)
    const bool rok0 = (h >= 1), rok2 = (h <= H_ - 2);
    const bool cok0 = (wi >= 1), cok2 = (wi <= W_ - 2);
    const bool ok[3][3] = {
        { rok0 && cok0, rok0, rok0 && cok2 },
        { cok0,         true, cok2         },
        { rok2 && cok0, rok2, rok2 && cok2 },
    };

    const float* ib = inp + (size_t)(n * C_ + chalf * 24) * HW + (wi - 1);
    float* outb = out + ((size_t)(n * C_ + chalf * 24) * HO + h * 8 + pg * 2) * WO
                      + wi * 8 + q4 * 4;

    // taps for ONE channel (cached loads; inp is L2-resident)
    auto load_ch = [&](int cp, float* tp) {
        #pragma unroll
        for (int di = 0; di < 3; ++di)
            #pragma unroll
            for (int dj = 0; dj < 3; ++dj) {
                const float* p = ib + (size_t)(cp * H_ + h - 1 + di) * W_ + dj;
                tp[di * 3 + dj] = ok[di][dj] ? *p : 0.f;
            }
    };
    // FMA + 2 nt stores for one channel
    auto do_ch = [&](int cp, const float* tp) {
        #pragma unroll
        for (int pl = 0; pl < 2; ++pl) {
            f32x4 acc = w[pl][0] * tp[0];
            #pragma unroll
            for (int k = 1; k < 9; ++k)
                acc += w[pl][k] * tp[k];
            __builtin_nontemporal_store(acc,
                (f32x4*)(outb + ((size_t)cp * HO + pl) * WO));
        }
    };

    // software pipeline: loads(i+1) issue before stores(i)
    float tpA[9], tpB[9];
    load_ch(0, tpA);
    #pragma unroll 2
    for (int it = 0; it < 24; ++it) {
        float* cur = (it & 1) ? tpB : tpA;
        float* nxt = (it & 1) ? tpA : tpB;
        if (it < 23) load_ch(it + 1, nxt);   // issued BEFORE stores of it
        do_ch(it, cur);
    }
}

extern "C" void kernel_launch(void* const* d_in, const int* in_sizes, int n_in,
                              void* d_out, int out_size, void* d_ws, size_t ws_size,
                              hipStream_t stream) {
    const float* inp  = (const float*)d_in[0];
    const float* mask = (const float*)d_in[1];
    float* out = (float*)d_out;
    const int blocks = N_ * H_ * 4;   // 8*48*4 = 1536
    raft_up_kernel<<<blocks, 256, 0, stream>>>(inp, mask, out);
}

// Round 16
// 67.618 us; speedup vs baseline: 8.7926x; 1.2784x over previous
//
#include <hip/hip_runtime.h>

#define N_ 8
#define C_ 48
#define H_ 48
#define W_ 64
#define HO 384
#define WO 512
#define HW (H_*W_)   // 3072

typedef float f32x4 __attribute__((ext_vector_type(4)));

// out[n][c][h*8+p][w*8+q] = sum_k softmax_k(mask[n][k*64+p*8+q][h][w]) * inp_pad[n][c][h+di-1][w+dj-1]
// R11 (84.2us) with ONE change: mask loads are CACHED again (nt removed).
// Rationale: chalf=0/1 thread halves read identical mask addresses; nt loads
// may force the duplicate read to HBM (mask fetch x2). Stores remain nt
// (confirmed win: output is never re-read, keep it out of L2).
__global__ __launch_bounds__(256, 3) void raft_up_kernel(
    const float* __restrict__ inp, const float* __restrict__ mask,
    float* __restrict__ out)
{
    const int t   = threadIdx.x;
    const int bid = blockIdx.x;            // (n*H + h)*4 + pg
    const int pg  = bid & 3;
    const int h   = (bid >> 2) % H_;
    const int n   = bid / (4 * H_);

    const int tq    = t & 127;
    const int chalf = t >> 7;              // 0: c 0..23, 1: c 24..47
    const int q4    = tq & 1;              // q quad (q = q4*4 + j)
    const int wi    = tq >> 1;             // 0..63 (w coordinate)

    // ---- softmax over 9 taps for my 8 planes (pl x 4 q's); f32x4 lanes = j (q)
    f32x4 w[2][9];
    {
        const float* mb = mask + ((size_t)n * 576 + pg * 16 + q4 * 4) * HW
                               + h * W_ + wi;
        #pragma unroll
        for (int pl = 0; pl < 2; ++pl)
            #pragma unroll
            for (int k = 0; k < 9; ++k)
                #pragma unroll
                for (int j = 0; j < 4; ++j)
                    w[pl][k][j] = mb[(size_t)(k * 64 + pl * 8 + j) * HW];

        #pragma unroll
        for (int pl = 0; pl < 2; ++pl) {
            f32x4 mx = w[pl][0];
            #pragma unroll
            for (int k = 1; k < 9; ++k) {
                mx.x = fmaxf(mx.x, w[pl][k].x); mx.y = fmaxf(mx.y, w[pl][k].y);
                mx.z = fmaxf(mx.z, w[pl][k].z); mx.w = fmaxf(mx.w, w[pl][k].w);
            }
            f32x4 s = (f32x4){0.f, 0.f, 0.f, 0.f};
            #pragma unroll
            for (int k = 0; k < 9; ++k) {
                f32x4 e;
                e.x = __expf(w[pl][k].x - mx.x);
                e.y = __expf(w[pl][k].y - mx.y);
                e.z = __expf(w[pl][k].z - mx.z);
                e.w = __expf(w[pl][k].w - mx.w);
                w[pl][k] = e;
                s += e;
            }
            f32x4 inv;
            inv.x = 1.f / s.x; inv.y = 1.f / s.y;
            inv.z = 1.f / s.z; inv.w = 1.f / s.w;
            #pragma unroll
            for (int k = 0; k < 9; ++k) w[pl][k] *= inv;
        }
    }

    // ---- tap validity (zero padding)
    const bool rok0 = (h >= 1), rok2 = (h <= H_ - 2);
    const bool cok0 = (wi >= 1), cok2 = (wi <= W_ - 2);
    const bool ok[3][3] = {
        { rok0 && cok0, rok0, rok0 && cok2 },
        { cok0,         true, cok2         },
        { rok2 && cok0, rok2, rok2 && cok2 },
    };

    const float* ib = inp + (size_t)(n * C_ + chalf * 24) * HW + (wi - 1);
    float* outb = out + ((size_t)(n * C_ + chalf * 24) * HO + h * 8 + pg * 2) * WO
                      + wi * 8 + q4 * 4;

    for (int cblk = 0; cblk < 6; ++cblk) {
        // taps for 4 channels, read from L2-resident inp (cached loads)
        float tp[4][9];
        #pragma unroll
        for (int di = 0; di < 3; ++di)
            #pragma unroll
            for (int dj = 0; dj < 3; ++dj) {
                const bool o = ok[di][dj];
                #pragma unroll
                for (int cc = 0; cc < 4; ++cc) {
                    const float* p = ib + (size_t)((cblk * 4 + cc) * H_ + h - 1 + di) * W_ + dj;
                    tp[cc][di * 3 + dj] = o ? *p : 0.f;
                }
            }
        #pragma unroll
        for (int cc = 0; cc < 4; ++cc)
            #pragma unroll
            for (int pl = 0; pl < 2; ++pl) {
                f32x4 acc = w[pl][0] * tp[cc][0];
                #pragma unroll
                for (int k = 1; k < 9; ++k)
                    acc += w[pl][k] * tp[cc][k];
                __builtin_nontemporal_store(acc,
                    (f32x4*)(outb + ((size_t)(cblk * 4 + cc) * HO + pl) * WO));
            }
    }
}

extern "C" void kernel_launch(void* const* d_in, const int* in_sizes, int n_in,
                              void* d_out, int out_size, void* d_ws, size_t ws_size,
                              hipStream_t stream) {
    const float* inp  = (const float*)d_in[0];
    const float* mask = (const float*)d_in[1];
    float* out = (float*)d_out;
    const int blocks = N_ * H_ * 4;   // 8*48*4 = 1536
    raft_up_kernel<<<blocks, 256, 0, stream>>>(inp, mask, out);
}

// Round 17
// 66.776 us; speedup vs baseline: 8.9035x; 1.0126x over previous
//
#include <hip/hip_runtime.h>

#define N_ 8
#define C_ 48
#define H_ 48
#define W_ 64
#define HO 384
#define WO 512
#define HW (H_*W_)   // 3072

typedef float f32x4 __attribute__((ext_vector_type(4)));

// out[n][c][h*8+p][w*8+q] = sum_k softmax_k(mask[n][k*64+p*8+q][h][w]) * inp_pad[n][c][h+di-1][w+dj-1]
// R16 (67.6us: zero-LDS, cached mask loads, nt stores) + ONE change:
// pl=1 mask loads (half the HBM read phase) are issued AFTER cblk0's pl=0
// stores, so their traffic overlaps the write stream instead of serializing
// in front of it. Only cblk0 loses 4KB-chunk adjacency (4 of 24 channels).
__global__ __launch_bounds__(256, 3) void raft_up_kernel(
    const float* __restrict__ inp, const float* __restrict__ mask,
    float* __restrict__ out)
{
    const int t   = threadIdx.x;
    const int bid = blockIdx.x;            // (n*H + h)*4 + pg
    const int pg  = bid & 3;
    const int h   = (bid >> 2) % H_;
    const int n   = bid / (4 * H_);

    const int tq    = t & 127;
    const int chalf = t >> 7;              // 0: c 0..23, 1: c 24..47
    const int q4    = tq & 1;              // q quad (q = q4*4 + j)
    const int wi    = tq >> 1;             // 0..63 (w coordinate)

    const float* mb = mask + ((size_t)n * 576 + pg * 16 + q4 * 4) * HW
                           + h * W_ + wi;

    auto softmax9 = [](f32x4* v) {
        f32x4 mx = v[0];
        #pragma unroll
        for (int k = 1; k < 9; ++k) {
            mx.x = fmaxf(mx.x, v[k].x); mx.y = fmaxf(mx.y, v[k].y);
            mx.z = fmaxf(mx.z, v[k].z); mx.w = fmaxf(mx.w, v[k].w);
        }
        f32x4 s = (f32x4){0.f, 0.f, 0.f, 0.f};
        #pragma unroll
        for (int k = 0; k < 9; ++k) {
            f32x4 e;
            e.x = __expf(v[k].x - mx.x);
            e.y = __expf(v[k].y - mx.y);
            e.z = __expf(v[k].z - mx.z);
            e.w = __expf(v[k].w - mx.w);
            v[k] = e;
            s += e;
        }
        f32x4 inv;
        inv.x = 1.f / s.x; inv.y = 1.f / s.y;
        inv.z = 1.f / s.z; inv.w = 1.f / s.w;
        #pragma unroll
        for (int k = 0; k < 9; ++k) v[k] *= inv;
    };

    // ---- pl=0 mask loads + softmax (front of kernel)
    f32x4 w0[9];
    #pragma unroll
    for (int k = 0; k < 9; ++k)
        #pragma unroll
        for (int j = 0; j < 4; ++j)
            w0[k][j] = mb[(size_t)(k * 64 + j) * HW];
    softmax9(w0);

    // ---- issue pl=1 mask loads NOW; consumed only after cblk0's pl0 stores
    f32x4 w1[9];
    #pragma unroll
    for (int k = 0; k < 9; ++k)
        #pragma unroll
        for (int j = 0; j < 4; ++j)
            w1[k][j] = mb[(size_t)(k * 64 + 8 + j) * HW];

    // ---- tap validity (zero padding)
    const bool rok0 = (h >= 1), rok2 = (h <= H_ - 2);
    const bool cok0 = (wi >= 1), cok2 = (wi <= W_ - 2);
    const bool ok[3][3] = {
        { rok0 && cok0, rok0, rok0 && cok2 },
        { cok0,         true, cok2         },
        { rok2 && cok0, rok2, rok2 && cok2 },
    };

    const float* ib = inp + (size_t)(n * C_ + chalf * 24) * HW + (wi - 1);
    float* outb = out + ((size_t)(n * C_ + chalf * 24) * HO + h * 8 + pg * 2) * WO
                      + wi * 8 + q4 * 4;

    auto load_taps = [&](int cblk, float tp[4][9]) {
        #pragma unroll
        for (int di = 0; di < 3; ++di)
            #pragma unroll
            for (int dj = 0; dj < 3; ++dj) {
                const bool o = ok[di][dj];
                #pragma unroll
                for (int cc = 0; cc < 4; ++cc) {
                    const float* p = ib + (size_t)((cblk * 4 + cc) * H_ + h - 1 + di) * W_ + dj;
                    tp[cc][di * 3 + dj] = o ? *p : 0.f;
                }
            }
    };
    auto store_pl = [&](int cblk, const float tp[4][9], const f32x4* w, int pl) {
        #pragma unroll
        for (int cc = 0; cc < 4; ++cc) {
            f32x4 acc = w[0] * tp[cc][0];
            #pragma unroll
            for (int k = 1; k < 9; ++k)
                acc += w[k] * tp[cc][k];
            __builtin_nontemporal_store(acc,
                (f32x4*)(outb + ((size_t)(cblk * 4 + cc) * HO + pl) * WO));
        }
    };

    // ---- cblk0: pl0 stores first (pl1 loads still in flight), then pl1
    {
        float tp[4][9];
        load_taps(0, tp);
        store_pl(0, tp, w0, 0);     // issued before any dependence on w1
        softmax9(w1);               // waitcnt for pl1 loads lands here
        store_pl(0, tp, w1, 1);
    }

    // ---- cblk1..5: normal both-pl (4KB chunks preserved)
    for (int cblk = 1; cblk < 6; ++cblk) {
        float tp[4][9];
        load_taps(cblk, tp);
        #pragma unroll
        for (int cc = 0; cc < 4; ++cc) {
            f32x4 a0 = w0[0] * tp[cc][0];
            f32x4 a1 = w1[0] * tp[cc][0];
            #pragma unroll
            for (int k = 1; k < 9; ++k) {
                a0 += w0[k] * tp[cc][k];
                a1 += w1[k] * tp[cc][k];
            }
            __builtin_nontemporal_store(a0,
                (f32x4*)(outb + ((size_t)(cblk * 4 + cc) * HO + 0) * WO));
            __builtin_nontemporal_store(a1,
                (f32x4*)(outb + ((size_t)(cblk * 4 + cc) * HO + 1) * WO));
        }
    }
}

extern "C" void kernel_launch(void* const* d_in, const int* in_sizes, int n_in,
                              void* d_out, int out_size, void* d_ws, size_t ws_size,
                              hipStream_t stream) {
    const float* inp  = (const float*)d_in[0];
    const float* mask = (const float*)d_in[1];
    float* out = (float*)d_out;
    const int blocks = N_ * H_ * 4;   // 8*48*4 = 1536
    raft_up_kernel<<<blocks, 256, 0, stream>>>(inp, mask, out);
}